// Round 1
// baseline (1014.704 us; speedup 1.0000x reference)
//
#include <hip/hip_runtime.h>
#include <math.h>

// SS2D constants
#define BB 4
#define DI 192
#define NS 16
#define LL 4096

__device__ __forceinline__ float softplusf(float x) {
  return (x > 20.f) ? x : log1pf(__expf(x));
}
__device__ __forceinline__ float siluf(float x) {
  return x / (1.f + __expf(-x));
}

// ---------------------------------------------------------------------------
// K1: xz = x(16384,96) @ in_proj_w(384,96)^T ; cols<192 -> xh (B,L,DI), rest -> z
__global__ __launch_bounds__(256) void k_inproj(
    const float* __restrict__ x, const float* __restrict__ w,
    float* __restrict__ xh, float* __restrict__ z) {
  __shared__ float As[64 * 97];
  __shared__ float Bs[64 * 97];
  const int t = threadIdx.x;
  const int bm = blockIdx.x, bn = blockIdx.y;
  const float* xrow = x + (size_t)bm * 64 * 96;
  const float* wrow = w + (size_t)bn * 64 * 96;
#pragma unroll
  for (int rep = 0; rep < 6; ++rep) {
    int fi = rep * 256 + t;
    int r = fi / 24, kq = (fi - r * 24) * 4;
    float4 av = *reinterpret_cast<const float4*>(xrow + r * 96 + kq);
    As[r * 97 + kq + 0] = av.x; As[r * 97 + kq + 1] = av.y;
    As[r * 97 + kq + 2] = av.z; As[r * 97 + kq + 3] = av.w;
    float4 bv = *reinterpret_cast<const float4*>(wrow + r * 96 + kq);
    Bs[r * 97 + kq + 0] = bv.x; Bs[r * 97 + kq + 1] = bv.y;
    Bs[r * 97 + kq + 2] = bv.z; Bs[r * 97 + kq + 3] = bv.w;
  }
  __syncthreads();
  const int tm = (t >> 4) * 4, tn = (t & 15) * 4;
  float acc[4][4] = {};
  for (int kk = 0; kk < 96; ++kk) {
    float av[4], bv[4];
#pragma unroll
    for (int i = 0; i < 4; ++i) av[i] = As[(tm + i) * 97 + kk];
#pragma unroll
    for (int j = 0; j < 4; ++j) bv[j] = Bs[(tn + j) * 97 + kk];
#pragma unroll
    for (int i = 0; i < 4; ++i)
#pragma unroll
      for (int j = 0; j < 4; ++j) acc[i][j] += av[i] * bv[j];
  }
  const int e0 = bn * 64 + tn;
#pragma unroll
  for (int i = 0; i < 4; ++i) {
    size_t m = (size_t)bm * 64 + tm + i;
    float4 v = make_float4(acc[i][0], acc[i][1], acc[i][2], acc[i][3]);
    if (e0 < DI) *reinterpret_cast<float4*>(xh + m * DI + e0) = v;
    else         *reinterpret_cast<float4*>(z + m * DI + (e0 - DI)) = v;
  }
}

// ---------------------------------------------------------------------------
// K2a: depthwise 3x3 SAME conv + bias + SiLU.  xh (B,H,W,DI) -> u0 (B,DI,H*W)
// block = (h, b), 192 threads (one per channel d)
__global__ __launch_bounds__(192) void k_conv(
    const float* __restrict__ xh, const float* __restrict__ cw,
    const float* __restrict__ cb, float* __restrict__ u0) {
  __shared__ float tile[DI * 65];
  const int h = blockIdx.x, b = blockIdx.y;
  const int d = threadIdx.x;
  float wgt[9];
#pragma unroll
  for (int i = 0; i < 9; ++i) wgt[i] = cw[d * 9 + i];
  const float bias = cb[d];
  const bool hm = (h > 0), hp = (h < 63);
  const float* rowm = xh + ((size_t)(b * 64 + (h - 1)) * 64) * DI + d;
  const float* row0 = xh + ((size_t)(b * 64 + h) * 64) * DI + d;
  const float* rowp = xh + ((size_t)(b * 64 + (h + 1)) * 64) * DI + d;
  float cp0 = 0.f, cp1 = 0.f, cp2 = 0.f;
  float cc0 = hm ? rowm[0] : 0.f;
  float cc1 = row0[0];
  float cc2 = hp ? rowp[0] : 0.f;
  for (int w = 0; w < 64; ++w) {
    float cn0 = 0.f, cn1 = 0.f, cn2 = 0.f;
    if (w < 63) {
      cn0 = hm ? rowm[(w + 1) * DI] : 0.f;
      cn1 = row0[(w + 1) * DI];
      cn2 = hp ? rowp[(w + 1) * DI] : 0.f;
    }
    float acc = bias
      + cp0 * wgt[0] + cc0 * wgt[1] + cn0 * wgt[2]
      + cp1 * wgt[3] + cc1 * wgt[4] + cn1 * wgt[5]
      + cp2 * wgt[6] + cc2 * wgt[7] + cn2 * wgt[8];
    tile[d * 65 + w] = siluf(acc);
    cp0 = cc0; cp1 = cc1; cp2 = cc2;
    cc0 = cn0; cc1 = cn1; cc2 = cn2;
  }
  __syncthreads();
  const int lane = threadIdx.x & 63, wid = threadIdx.x >> 6;  // wid 0..2
  for (int j = 0; j < 64; ++j) {
    int dr = j * 3 + wid;
    u0[((size_t)(b * DI + dr)) * LL + h * 64 + lane] = tile[dr * 65 + lane];
  }
}

// ---------------------------------------------------------------------------
// K2b: u1[b,d, w*64+h] = u0[b,d, h*64+w]   (64x64 transpose per (b,d))
__global__ __launch_bounds__(256) void k_transpose(
    const float* __restrict__ u0, float* __restrict__ u1) {
  __shared__ float t[64 * 65];
  const int bd = blockIdx.x;
  const float* src = u0 + (size_t)bd * LL;
  float* dst = u1 + (size_t)bd * LL;
  const int lane = threadIdx.x & 63, q = threadIdx.x >> 6;
  for (int r = 0; r < 16; ++r) {
    int hh = r * 4 + q;
    t[hh * 65 + lane] = src[hh * 64 + lane];
  }
  __syncthreads();
  for (int r = 0; r < 16; ++r) {
    int ww = r * 4 + q;
    dst[ww * 64 + lane] = t[lane * 65 + ww];
  }
}

// ---------------------------------------------------------------------------
// K3: x_dbl = xs @ x_proj_w^T per (b,k).  Outputs stored in scan-transposed
// layout a = i*64 + c  where scan index l = c*64 + i.
// block = (i, k, b), 256 threads
__global__ __launch_bounds__(256) void k_xdbl(
    const float* __restrict__ u0, const float* __restrict__ u1,
    const float* __restrict__ xpw, float* __restrict__ dts,
    float* __restrict__ Bsv, float* __restrict__ Csv) {
  __shared__ float X[DI * 64];
  const int i = blockIdx.x, k = blockIdx.y, b = blockIdx.z;
  const int c = threadIdx.x & 63, g = threadIdx.x >> 6;  // g 0..3
  const float* u = (k & 1) ? u0 : u1;
  const int a = i * 64 + c;
  const int addr = (k < 2) ? a : (4095 - a);
  for (int dd = 0; dd < 48; ++dd) {
    int d = dd * 4 + g;
    X[d * 64 + c] = u[((size_t)(b * DI + d)) * LL + addr];
  }
  __syncthreads();
  float acc[10];
#pragma unroll
  for (int j = 0; j < 10; ++j) acc[j] = 0.f;
  const float* wbase = xpw + (size_t)k * 38 * DI;
  for (int d = 0; d < DI; ++d) {
    float xv = X[d * 64 + c];
#pragma unroll
    for (int j = 0; j < 10; ++j) {
      int co = g * 10 + j;
      if (co < 38) acc[j] += xv * wbase[co * DI + d];
    }
  }
  const int bk = b * 4 + k;
#pragma unroll
  for (int j = 0; j < 10; ++j) {
    int co = g * 10 + j;
    if (co < 38) {
      float v = acc[j];
      if (co < 6)       dts[((size_t)bk * 6 + co) * LL + a] = v;
      else if (co < 22) Bsv[((size_t)bk * 16 + (co - 6)) * LL + a] = v;
      else              Csv[((size_t)bk * 16 + (co - 22)) * LL + a] = v;
    }
  }
}

// ---------------------------------------------------------------------------
// K4: scan pass 1 — per-chunk local scan from h=0; emits h_out (16) and sum(delta)
// block = (dgroup, k, b), 256 thr; wave w handles d = dgroup*4+w, lane c = chunk
__global__ __launch_bounds__(256) void k_scan1(
    const float* __restrict__ u0, const float* __restrict__ u1,
    const float* __restrict__ dts, const float* __restrict__ Bsv,
    const float* __restrict__ dtw, const float* __restrict__ dtb,
    const float* __restrict__ alog,
    float* __restrict__ hbuf, float* __restrict__ sumd) {
  const int dg = blockIdx.x, k = blockIdx.y, b = blockIdx.z;
  const int c = threadIdx.x & 63, wv = threadIdx.x >> 6;
  const int d = dg * 4 + wv;
  const int kd = k * DI + d;
  const int bk = b * 4 + k;
  float A[NS];
#pragma unroll
  for (int n = 0; n < NS; ++n) A[n] = -__expf(alog[kd * NS + n]);
  float wdt[6];
#pragma unroll
  for (int r = 0; r < 6; ++r) wdt[r] = dtw[kd * 6 + r];
  const float bdt = dtb[kd];
  const float* uptr = (k & 1) ? u0 : u1;
  const size_t ubase = ((size_t)(b * DI + d)) * LL;
  const float* dbase = dts + (size_t)bk * 6 * LL;
  const float* Bbase = Bsv + (size_t)bk * 16 * LL;
  float h[NS];
#pragma unroll
  for (int n = 0; n < NS; ++n) h[n] = 0.f;
  float sd = 0.f;
  for (int i = 0; i < 64; ++i) {
    const int a = i * 64 + c;
    float dl = bdt;
#pragma unroll
    for (int r = 0; r < 6; ++r) dl += dbase[r * LL + a] * wdt[r];
    dl = softplusf(dl);
    const int ua = (k < 2) ? a : (4095 - a);
    const float uu = uptr[ubase + ua];
    const float du = dl * uu;
    sd += dl;
#pragma unroll
    for (int n = 0; n < NS; ++n) {
      const float Bv = Bbase[n * LL + a];
      h[n] = h[n] * __expf(dl * A[n]) + du * Bv;
    }
  }
  const size_t hb = ((size_t)(bk * DI + d) * 64 + c) * NS;
  float4* hp = reinterpret_cast<float4*>(hbuf + hb);
  hp[0] = make_float4(h[0], h[1], h[2], h[3]);
  hp[1] = make_float4(h[4], h[5], h[6], h[7]);
  hp[2] = make_float4(h[8], h[9], h[10], h[11]);
  hp[3] = make_float4(h[12], h[13], h[14], h[15]);
  sumd[(size_t)(bk * DI + d) * 64 + c] = sd;
}

// ---------------------------------------------------------------------------
// K5: scan pass 2 — exclusive scan over the 64 chunks (in place in hbuf).
// thread per (bkd, n) ; 192 blocks x 256
__global__ __launch_bounds__(256) void k_scan2(
    const float* __restrict__ alog, const float* __restrict__ sumd,
    float* __restrict__ hbuf) {
  const int tg = blockIdx.x * 256 + threadIdx.x;
  const int bkd = tg >> 4, n = tg & 15;
  const int kd = bkd % (4 * DI);
  const float An = -__expf(alog[kd * NS + n]);
  float h = 0.f;
  const size_t base = (size_t)bkd * 64;
  for (int cc = 0; cc < 64; ++cc) {
    const float hv = hbuf[(base + cc) * NS + n];
    const float sdv = sumd[base + cc];
    const float wdec = __expf(An * sdv);
    hbuf[(base + cc) * NS + n] = h;   // h entering chunk cc
    h = h * wdec + hv;
  }
}

// ---------------------------------------------------------------------------
// K6: scan pass 3 — re-run chunk from correct h_in, emit y into yacc (B,DI,L)
// spatial p-maps per direction; k in {0,2} transpose via swizzled LDS.
template <int KDIR, bool ACCUM>
__global__ __launch_bounds__(256) void k_scan3(
    const float* __restrict__ u0, const float* __restrict__ u1,
    const float* __restrict__ dts, const float* __restrict__ Bsv,
    const float* __restrict__ Csv,
    const float* __restrict__ dtw, const float* __restrict__ dtb,
    const float* __restrict__ alog, const float* __restrict__ hbuf,
    const float* __restrict__ Dsv, float* __restrict__ yacc) {
  __shared__ float ylds[(KDIR & 1) ? 4 : 4 * 4096];
  const int dg = blockIdx.x, b = blockIdx.y;
  const int c = threadIdx.x & 63, wv = threadIdx.x >> 6;
  const int d = dg * 4 + wv;
  const int kd = KDIR * DI + d;
  const int bk = b * 4 + KDIR;
  float A[NS];
#pragma unroll
  for (int n = 0; n < NS; ++n) A[n] = -__expf(alog[kd * NS + n]);
  float wdt[6];
#pragma unroll
  for (int r = 0; r < 6; ++r) wdt[r] = dtw[kd * 6 + r];
  const float bdt = dtb[kd];
  const float Dv = Dsv[kd];
  const float* uptr = (KDIR & 1) ? u0 : u1;
  const size_t ubase = ((size_t)(b * DI + d)) * LL;
  const float* dbase = dts + (size_t)bk * 6 * LL;
  const float* Bbase = Bsv + (size_t)bk * 16 * LL;
  const float* Cbase = Csv + (size_t)bk * 16 * LL;
  const size_t ybase = ((size_t)(b * DI + d)) * LL;
  float h[NS];
  {
    const size_t hb = ((size_t)(bk * DI + d) * 64 + c) * NS;
    const float4* hp = reinterpret_cast<const float4*>(hbuf + hb);
#pragma unroll
    for (int q = 0; q < 4; ++q) {
      float4 v = hp[q];
      h[q * 4 + 0] = v.x; h[q * 4 + 1] = v.y; h[q * 4 + 2] = v.z; h[q * 4 + 3] = v.w;
    }
  }
  for (int i = 0; i < 64; ++i) {
    const int a = i * 64 + c;
    float dl = bdt;
#pragma unroll
    for (int r = 0; r < 6; ++r) dl += dbase[r * LL + a] * wdt[r];
    dl = softplusf(dl);
    const int ua = (KDIR < 2) ? a : (4095 - a);
    const float uu = uptr[ubase + ua];
    const float du = dl * uu;
    float yv = Dv * uu;
#pragma unroll
    for (int n = 0; n < NS; ++n) {
      const float Bv = Bbase[n * LL + a];
      const float Cv = Cbase[n * LL + a];
      h[n] = h[n] * __expf(dl * A[n]) + du * Bv;
      yv += h[n] * Cv;
    }
    if (KDIR == 1) {
      const size_t ya = ybase + a;
      if (ACCUM) yacc[ya] += yv; else yacc[ya] = yv;
    } else if (KDIR == 3) {
      const size_t ya = ybase + (4095 - a);
      if (ACCUM) yacc[ya] += yv; else yacc[ya] = yv;
    } else {
      ylds[wv * 4096 + c * 64 + ((i + c) & 63)] = yv;  // swizzled, conflict-free
    }
  }
  if (KDIR == 0 || KDIR == 2) {
    __syncthreads();
    for (int j = 0; j < 64; ++j) {
      float v;
      if (KDIR == 0) {
        v = ylds[wv * 4096 + j * 64 + ((c + j) & 63)];
      } else {
        const int cj = 63 - j, ii = 63 - c;
        v = ylds[wv * 4096 + cj * 64 + ((ii + cj) & 63)];
      }
      const size_t ya = ybase + j * 64 + c;
      if (ACCUM) yacc[ya] += v; else yacc[ya] = v;
    }
  }
}

// ---------------------------------------------------------------------------
// K7: LayerNorm(d) * SiLU(z) then out = y @ out_proj_w^T  -> (B,L,96)
// block = (ptile, b), 256 threads
__global__ __launch_bounds__(256) void k_lnout(
    const float* __restrict__ yacc, const float* __restrict__ z,
    const float* __restrict__ lng, const float* __restrict__ lnb,
    const float* __restrict__ opw, float* __restrict__ out) {
  __shared__ float ytile[64 * 193];
  const int pt = blockIdx.x, b = blockIdx.y;
  const int t = threadIdx.x;
  {
    const int c = t & 63, q4 = t >> 6;
    for (int dd = 0; dd < 48; ++dd) {
      int d = dd * 4 + q4;
      ytile[c * 193 + d] = yacc[((size_t)(b * DI + d)) * LL + pt * 64 + c];
    }
  }
  __syncthreads();
  {
    const int p = t >> 2, qq = t & 3;
    float s = 0.f, s2 = 0.f;
    for (int j = 0; j < 48; ++j) {
      float v = ytile[p * 193 + qq * 48 + j];
      s += v; s2 += v * v;
    }
    s += __shfl_xor(s, 1, 64);  s += __shfl_xor(s, 2, 64);
    s2 += __shfl_xor(s2, 1, 64); s2 += __shfl_xor(s2, 2, 64);
    const float mu = s * (1.f / 192.f);
    const float var = s2 * (1.f / 192.f) - mu * mu;
    const float rstd = rsqrtf(var + 1e-5f);
    const size_t prow = ((size_t)b * LL + pt * 64 + p) * DI;
    for (int j = 0; j < 48; ++j) {
      int d = qq * 48 + j;
      float v = (ytile[p * 193 + d] - mu) * rstd * lng[d] + lnb[d];
      float zv = z[prow + d];
      v *= siluf(zv);
      ytile[p * 193 + d] = v;
    }
  }
  __syncthreads();
  float acc[24];
#pragma unroll
  for (int j = 0; j < 24; ++j) acc[j] = 0.f;
  const int p2 = t & 63, gq = t >> 6;
  for (int d = 0; d < DI; ++d) {
    float yv = ytile[p2 * 193 + d];
#pragma unroll
    for (int j = 0; j < 24; ++j) acc[j] += yv * opw[(gq * 24 + j) * DI + d];
  }
  __syncthreads();
  float* l2 = ytile;  // reuse as [64][97]
#pragma unroll
  for (int j = 0; j < 24; ++j) l2[p2 * 97 + gq * 24 + j] = acc[j];
  __syncthreads();
  for (int rr = 0; rr < 24; ++rr) {
    int idx = rr * 256 + t;
    int pp = idx / 96, cc = idx - pp * 96;
    out[((size_t)b * LL + pt * 64 + pp) * 96 + cc] = l2[pp * 97 + cc];
  }
}

// ---------------------------------------------------------------------------
extern "C" void kernel_launch(void* const* d_in, const int* in_sizes, int n_in,
                              void* d_out, int out_size, void* d_ws, size_t ws_size,
                              hipStream_t stream) {
  const float* x          = (const float*)d_in[0];
  const float* in_proj_w  = (const float*)d_in[1];
  const float* conv_w     = (const float*)d_in[2];
  const float* conv_b     = (const float*)d_in[3];
  const float* x_proj_w   = (const float*)d_in[4];
  const float* dt_projs_w = (const float*)d_in[5];
  const float* dt_projs_b = (const float*)d_in[6];
  const float* A_logs     = (const float*)d_in[7];
  const float* Ds         = (const float*)d_in[8];
  const float* ln_g       = (const float*)d_in[9];
  const float* ln_b       = (const float*)d_in[10];
  const float* out_proj_w = (const float*)d_in[11];
  float* out = (float*)d_out;
  float* ws = (float*)d_ws;
  // workspace layout (floats): total 21,561,344 (86.2 MB)
  float* xh   = ws;               // 3145728  (B,L,DI)
  float* z    = ws + 3145728;     // 3145728  (B,L,DI)
  float* u0   = ws + 6291456;     // 3145728  (B,DI,H*W) row-major spatial
  float* u1   = ws + 9437184;     // 3145728  (B,DI,W*H) transposed spatial
  float* dts  = ws + 12582912;    // 393216   (B,K,6,L) scan-transposed
  float* Bsv  = ws + 12976128;    // 1048576  (B,K,16,L) scan-transposed
  float* Csv  = ws + 14024704;    // 1048576
  float* hbuf = ws + 15073280;    // 3145728  (B,K,DI,64 chunks,16)
  float* sumd = ws + 18219008;    // 196608   (B,K,DI,64)
  float* yacc = ws + 18415616;    // 3145728  (B,DI,L) merged directions

  k_inproj<<<dim3(256, 6), dim3(256), 0, stream>>>(x, in_proj_w, xh, z);
  k_conv<<<dim3(64, 4), dim3(192), 0, stream>>>(xh, conv_w, conv_b, u0);
  k_transpose<<<dim3(768), dim3(256), 0, stream>>>(u0, u1);
  k_xdbl<<<dim3(64, 4, 4), dim3(256), 0, stream>>>(u0, u1, x_proj_w, dts, Bsv, Csv);
  k_scan1<<<dim3(48, 4, 4), dim3(256), 0, stream>>>(u0, u1, dts, Bsv,
      dt_projs_w, dt_projs_b, A_logs, hbuf, sumd);
  k_scan2<<<dim3(192), dim3(256), 0, stream>>>(A_logs, sumd, hbuf);
  k_scan3<0, false><<<dim3(48, 4), dim3(256), 0, stream>>>(u0, u1, dts, Bsv, Csv,
      dt_projs_w, dt_projs_b, A_logs, hbuf, Ds, yacc);
  k_scan3<1, true><<<dim3(48, 4), dim3(256), 0, stream>>>(u0, u1, dts, Bsv, Csv,
      dt_projs_w, dt_projs_b, A_logs, hbuf, Ds, yacc);
  k_scan3<2, true><<<dim3(48, 4), dim3(256), 0, stream>>>(u0, u1, dts, Bsv, Csv,
      dt_projs_w, dt_projs_b, A_logs, hbuf, Ds, yacc);
  k_scan3<3, true><<<dim3(48, 4), dim3(256), 0, stream>>>(u0, u1, dts, Bsv, Csv,
      dt_projs_w, dt_projs_b, A_logs, hbuf, Ds, yacc);
  k_lnout<<<dim3(64, 4), dim3(256), 0, stream>>>(yacc, z, ln_g, ln_b, out_proj_w, out);
}

// Round 2
// 722.753 us; speedup vs baseline: 1.4039x; 1.4039x over previous
//
#include <hip/hip_runtime.h>
#include <math.h>

// SS2D constants
#define BB 4
#define DI 192
#define NS 16
#define LL 4096

__device__ __forceinline__ float softplusf(float x) {
  return (x > 20.f) ? x : log1pf(__expf(x));
}
__device__ __forceinline__ float siluf(float x) {
  return x / (1.f + __expf(-x));
}

// ---------------------------------------------------------------------------
// K1: xz = x(16384,96) @ in_proj_w(384,96)^T ; cols<192 -> xh (B,L,DI), rest -> z
__global__ __launch_bounds__(256) void k_inproj(
    const float* __restrict__ x, const float* __restrict__ w,
    float* __restrict__ xh, float* __restrict__ z) {
  __shared__ float As[64 * 97];
  __shared__ float Bs[64 * 97];
  const int t = threadIdx.x;
  const int bm = blockIdx.x, bn = blockIdx.y;
  const float* xrow = x + (size_t)bm * 64 * 96;
  const float* wrow = w + (size_t)bn * 64 * 96;
#pragma unroll
  for (int rep = 0; rep < 6; ++rep) {
    int fi = rep * 256 + t;
    int r = fi / 24, kq = (fi - r * 24) * 4;
    float4 av = *reinterpret_cast<const float4*>(xrow + r * 96 + kq);
    As[r * 97 + kq + 0] = av.x; As[r * 97 + kq + 1] = av.y;
    As[r * 97 + kq + 2] = av.z; As[r * 97 + kq + 3] = av.w;
    float4 bv = *reinterpret_cast<const float4*>(wrow + r * 96 + kq);
    Bs[r * 97 + kq + 0] = bv.x; Bs[r * 97 + kq + 1] = bv.y;
    Bs[r * 97 + kq + 2] = bv.z; Bs[r * 97 + kq + 3] = bv.w;
  }
  __syncthreads();
  const int tm = (t >> 4) * 4, tn = (t & 15) * 4;
  float acc[4][4] = {};
  for (int kk = 0; kk < 96; ++kk) {
    float av[4], bv[4];
#pragma unroll
    for (int i = 0; i < 4; ++i) av[i] = As[(tm + i) * 97 + kk];
#pragma unroll
    for (int j = 0; j < 4; ++j) bv[j] = Bs[(tn + j) * 97 + kk];
#pragma unroll
    for (int i = 0; i < 4; ++i)
#pragma unroll
      for (int j = 0; j < 4; ++j) acc[i][j] += av[i] * bv[j];
  }
  const int e0 = bn * 64 + tn;
#pragma unroll
  for (int i = 0; i < 4; ++i) {
    size_t m = (size_t)bm * 64 + tm + i;
    float4 v = make_float4(acc[i][0], acc[i][1], acc[i][2], acc[i][3]);
    if (e0 < DI) *reinterpret_cast<float4*>(xh + m * DI + e0) = v;
    else         *reinterpret_cast<float4*>(z + m * DI + (e0 - DI)) = v;
  }
}

// ---------------------------------------------------------------------------
// K2a: depthwise 3x3 SAME conv + bias + SiLU.  xh (B,H,W,DI) -> u0 (B,DI,H*W)
__global__ __launch_bounds__(192) void k_conv(
    const float* __restrict__ xh, const float* __restrict__ cw,
    const float* __restrict__ cb, float* __restrict__ u0) {
  __shared__ float tile[DI * 65];
  const int h = blockIdx.x, b = blockIdx.y;
  const int d = threadIdx.x;
  float wgt[9];
#pragma unroll
  for (int i = 0; i < 9; ++i) wgt[i] = cw[d * 9 + i];
  const float bias = cb[d];
  const bool hm = (h > 0), hp = (h < 63);
  const float* rowm = xh + ((size_t)(b * 64 + (h - 1)) * 64) * DI + d;
  const float* row0 = xh + ((size_t)(b * 64 + h) * 64) * DI + d;
  const float* rowp = xh + ((size_t)(b * 64 + (h + 1)) * 64) * DI + d;
  float cp0 = 0.f, cp1 = 0.f, cp2 = 0.f;
  float cc0 = hm ? rowm[0] : 0.f;
  float cc1 = row0[0];
  float cc2 = hp ? rowp[0] : 0.f;
  for (int w = 0; w < 64; ++w) {
    float cn0 = 0.f, cn1 = 0.f, cn2 = 0.f;
    if (w < 63) {
      cn0 = hm ? rowm[(w + 1) * DI] : 0.f;
      cn1 = row0[(w + 1) * DI];
      cn2 = hp ? rowp[(w + 1) * DI] : 0.f;
    }
    float acc = bias
      + cp0 * wgt[0] + cc0 * wgt[1] + cn0 * wgt[2]
      + cp1 * wgt[3] + cc1 * wgt[4] + cn1 * wgt[5]
      + cp2 * wgt[6] + cc2 * wgt[7] + cn2 * wgt[8];
    tile[d * 65 + w] = siluf(acc);
    cp0 = cc0; cp1 = cc1; cp2 = cc2;
    cc0 = cn0; cc1 = cn1; cc2 = cn2;
  }
  __syncthreads();
  const int lane = threadIdx.x & 63, wid = threadIdx.x >> 6;  // wid 0..2
  for (int j = 0; j < 64; ++j) {
    int dr = j * 3 + wid;
    u0[((size_t)(b * DI + dr)) * LL + h * 64 + lane] = tile[dr * 65 + lane];
  }
}

// ---------------------------------------------------------------------------
// K2b: u1[b,d, w*64+h] = u0[b,d, h*64+w]
__global__ __launch_bounds__(256) void k_transpose(
    const float* __restrict__ u0, float* __restrict__ u1) {
  __shared__ float t[64 * 65];
  const int bd = blockIdx.x;
  const float* src = u0 + (size_t)bd * LL;
  float* dst = u1 + (size_t)bd * LL;
  const int lane = threadIdx.x & 63, q = threadIdx.x >> 6;
  for (int r = 0; r < 16; ++r) {
    int hh = r * 4 + q;
    t[hh * 65 + lane] = src[hh * 64 + lane];
  }
  __syncthreads();
  for (int r = 0; r < 16; ++r) {
    int ww = r * 4 + q;
    dst[ww * 64 + lane] = t[lane * 65 + ww];
  }
}

// ---------------------------------------------------------------------------
// K3: x_dbl = xs @ x_proj_w^T per (b,k).  W staged in LDS (padded to 40 rows),
// register tile 5 rows x 2 cols per thread.  Outputs in scan-transposed layout
// a = i*64 + c  where scan index l = c*64 + i.
__global__ __launch_bounds__(256) void k_xdbl(
    const float* __restrict__ u0, const float* __restrict__ u1,
    const float* __restrict__ xpw, float* __restrict__ dts,
    float* __restrict__ Bsv, float* __restrict__ Csv) {
  __shared__ float X[DI * 64];    // [d][c]  48 KB
  __shared__ float Wl[40 * DI];   // [co][d] 30.7 KB (rows 38,39 zeroed)
  const int i = blockIdx.x, k = blockIdx.y, b = blockIdx.z;
  const int t = threadIdx.x;
  // stage W (1824 real float4s, pad to 1920 with zeros)
  {
    const float4* wsrc = reinterpret_cast<const float4*>(xpw + (size_t)k * 38 * DI);
    float4* wdst = reinterpret_cast<float4*>(Wl);
#pragma unroll
    for (int r = 0; r < 8; ++r) {
      int q = r * 256 + t;
      if (q < 1920) {
        float4 v = (q < 1824) ? wsrc[q] : make_float4(0.f, 0.f, 0.f, 0.f);
        wdst[q] = v;
      }
    }
  }
  // stage X
  const int c64 = t & 63, g4 = t >> 6;
  const float* u = (k & 1) ? u0 : u1;
  const int a0 = i * 64 + c64;
  const int addr = (k < 2) ? a0 : (4095 - a0);
  for (int dd = 0; dd < 48; ++dd) {
    int d = dd * 4 + g4;
    X[d * 64 + c64] = u[((size_t)(b * DI + d)) * LL + addr];
  }
  __syncthreads();
  const int c = t & 31, g = t >> 5;  // g 0..7, rows co = g*5+j
  float acc[5][2];
#pragma unroll
  for (int j = 0; j < 5; ++j) { acc[j][0] = 0.f; acc[j][1] = 0.f; }
  for (int dq = 0; dq < 48; ++dq) {
    float4 w[5];
#pragma unroll
    for (int j = 0; j < 5; ++j)
      w[j] = *reinterpret_cast<const float4*>(&Wl[(g * 5 + j) * DI + dq * 4]);
    float x0[4], x1[4];
#pragma unroll
    for (int e = 0; e < 4; ++e) {
      x0[e] = X[(dq * 4 + e) * 64 + c];
      x1[e] = X[(dq * 4 + e) * 64 + c + 32];
    }
#pragma unroll
    for (int j = 0; j < 5; ++j) {
      acc[j][0] += w[j].x * x0[0] + w[j].y * x0[1] + w[j].z * x0[2] + w[j].w * x0[3];
      acc[j][1] += w[j].x * x1[0] + w[j].y * x1[1] + w[j].z * x1[2] + w[j].w * x1[3];
    }
  }
  const int bk = b * 4 + k;
#pragma unroll
  for (int j = 0; j < 5; ++j) {
    const int co = g * 5 + j;
    if (co < 38) {
#pragma unroll
      for (int e = 0; e < 2; ++e) {
        const int a = i * 64 + c + e * 32;
        const float v = acc[j][e];
        if (co < 6)       dts[((size_t)bk * 6 + co) * LL + a] = v;
        else if (co < 22) Bsv[((size_t)bk * 16 + (co - 6)) * LL + a] = v;
        else              Csv[((size_t)bk * 16 + (co - 22)) * LL + a] = v;
      }
    }
  }
}

// ---------------------------------------------------------------------------
// K4: scan pass 1 — per-chunk local scan from h=0; emits h_out (16) and sum(delta)
__global__ __launch_bounds__(256) void k_scan1(
    const float* __restrict__ u0, const float* __restrict__ u1,
    const float* __restrict__ dts, const float* __restrict__ Bsv,
    const float* __restrict__ dtw, const float* __restrict__ dtb,
    const float* __restrict__ alog,
    float* __restrict__ hbuf, float* __restrict__ sumd) {
  const int dg = blockIdx.x, k = blockIdx.y, b = blockIdx.z;
  const int c = threadIdx.x & 63, wv = threadIdx.x >> 6;
  const int d = dg * 4 + wv;
  const int kd = k * DI + d;
  const int bk = b * 4 + k;
  float A[NS];
#pragma unroll
  for (int n = 0; n < NS; ++n) A[n] = -__expf(alog[kd * NS + n]);
  float wdt[6];
#pragma unroll
  for (int r = 0; r < 6; ++r) wdt[r] = dtw[kd * 6 + r];
  const float bdt = dtb[kd];
  const float* uptr = (k & 1) ? u0 : u1;
  const size_t ubase = ((size_t)(b * DI + d)) * LL;
  const float* dbase = dts + (size_t)bk * 6 * LL;
  const float* Bbase = Bsv + (size_t)bk * 16 * LL;
  float h[NS];
#pragma unroll
  for (int n = 0; n < NS; ++n) h[n] = 0.f;
  float sd = 0.f;
  for (int i = 0; i < 64; ++i) {
    const int a = i * 64 + c;
    float dl = bdt;
#pragma unroll
    for (int r = 0; r < 6; ++r) dl += dbase[r * LL + a] * wdt[r];
    dl = softplusf(dl);
    const int ua = (k < 2) ? a : (4095 - a);
    const float uu = uptr[ubase + ua];
    const float du = dl * uu;
    sd += dl;
#pragma unroll
    for (int n = 0; n < NS; ++n) {
      const float Bv = Bbase[n * LL + a];
      h[n] = h[n] * __expf(dl * A[n]) + du * Bv;
    }
  }
  const size_t hb = ((size_t)(bk * DI + d) * 64 + c) * NS;
  float4* hp = reinterpret_cast<float4*>(hbuf + hb);
  hp[0] = make_float4(h[0], h[1], h[2], h[3]);
  hp[1] = make_float4(h[4], h[5], h[6], h[7]);
  hp[2] = make_float4(h[8], h[9], h[10], h[11]);
  hp[3] = make_float4(h[12], h[13], h[14], h[15]);
  sumd[(size_t)(bk * DI + d) * 64 + c] = sd;
}

// ---------------------------------------------------------------------------
// K5: scan pass 2 — exclusive scan over the 64 chunks (in place in hbuf).
__global__ __launch_bounds__(256) void k_scan2(
    const float* __restrict__ alog, const float* __restrict__ sumd,
    float* __restrict__ hbuf) {
  const int tg = blockIdx.x * 256 + threadIdx.x;
  const int bkd = tg >> 4, n = tg & 15;
  const int kd = bkd % (4 * DI);
  const float An = -__expf(alog[kd * NS + n]);
  float h = 0.f;
  const size_t base = (size_t)bkd * 64;
  for (int cc = 0; cc < 64; ++cc) {
    const float hv = hbuf[(base + cc) * NS + n];
    const float sdv = sumd[base + cc];
    const float wdec = __expf(An * sdv);
    hbuf[(base + cc) * NS + n] = h;   // h entering chunk cc
    h = h * wdec + hv;
  }
}

// ---------------------------------------------------------------------------
// K6: scan pass 3 — re-run chunk from correct h_in, emit y into yacc (B,DI,L)
template <int KDIR, bool ACCUM>
__global__ __launch_bounds__(256) void k_scan3(
    const float* __restrict__ u0, const float* __restrict__ u1,
    const float* __restrict__ dts, const float* __restrict__ Bsv,
    const float* __restrict__ Csv,
    const float* __restrict__ dtw, const float* __restrict__ dtb,
    const float* __restrict__ alog, const float* __restrict__ hbuf,
    const float* __restrict__ Dsv, float* __restrict__ yacc) {
  __shared__ float ylds[(KDIR & 1) ? 4 : 4 * 4096];
  const int dg = blockIdx.x, b = blockIdx.y;
  const int c = threadIdx.x & 63, wv = threadIdx.x >> 6;
  const int d = dg * 4 + wv;
  const int kd = KDIR * DI + d;
  const int bk = b * 4 + KDIR;
  float A[NS];
#pragma unroll
  for (int n = 0; n < NS; ++n) A[n] = -__expf(alog[kd * NS + n]);
  float wdt[6];
#pragma unroll
  for (int r = 0; r < 6; ++r) wdt[r] = dtw[kd * 6 + r];
  const float bdt = dtb[kd];
  const float Dv = Dsv[kd];
  const float* uptr = (KDIR & 1) ? u0 : u1;
  const size_t ubase = ((size_t)(b * DI + d)) * LL;
  const float* dbase = dts + (size_t)bk * 6 * LL;
  const float* Bbase = Bsv + (size_t)bk * 16 * LL;
  const float* Cbase = Csv + (size_t)bk * 16 * LL;
  const size_t ybase = ((size_t)(b * DI + d)) * LL;
  float h[NS];
  {
    const size_t hb = ((size_t)(bk * DI + d) * 64 + c) * NS;
    const float4* hp = reinterpret_cast<const float4*>(hbuf + hb);
#pragma unroll
    for (int q = 0; q < 4; ++q) {
      float4 v = hp[q];
      h[q * 4 + 0] = v.x; h[q * 4 + 1] = v.y; h[q * 4 + 2] = v.z; h[q * 4 + 3] = v.w;
    }
  }
  for (int i = 0; i < 64; ++i) {
    const int a = i * 64 + c;
    float dl = bdt;
#pragma unroll
    for (int r = 0; r < 6; ++r) dl += dbase[r * LL + a] * wdt[r];
    dl = softplusf(dl);
    const int ua = (KDIR < 2) ? a : (4095 - a);
    const float uu = uptr[ubase + ua];
    const float du = dl * uu;
    float yv = Dv * uu;
#pragma unroll
    for (int n = 0; n < NS; ++n) {
      const float Bv = Bbase[n * LL + a];
      const float Cv = Cbase[n * LL + a];
      h[n] = h[n] * __expf(dl * A[n]) + du * Bv;
      yv += h[n] * Cv;
    }
    if (KDIR == 1) {
      const size_t ya = ybase + a;
      if (ACCUM) yacc[ya] += yv; else yacc[ya] = yv;
    } else if (KDIR == 3) {
      const size_t ya = ybase + (4095 - a);
      if (ACCUM) yacc[ya] += yv; else yacc[ya] = yv;
    } else {
      ylds[wv * 4096 + c * 64 + ((i + c) & 63)] = yv;  // swizzled, conflict-free
    }
  }
  if (KDIR == 0 || KDIR == 2) {
    __syncthreads();
    for (int j = 0; j < 64; ++j) {
      float v;
      if (KDIR == 0) {
        v = ylds[wv * 4096 + j * 64 + ((c + j) & 63)];
      } else {
        const int cj = 63 - j, ii = 63 - c;
        v = ylds[wv * 4096 + cj * 64 + ((ii + cj) & 63)];
      }
      const size_t ya = ybase + j * 64 + c;
      if (ACCUM) yacc[ya] += v; else yacc[ya] = v;
    }
  }
}

// ---------------------------------------------------------------------------
// K7: LayerNorm(d) * SiLU(z) then out = y @ out_proj_w^T  -> (B,L,96)
// out_proj_w staged in LDS; GEMM phase FMA-bound.
__global__ __launch_bounds__(256) void k_lnout(
    const float* __restrict__ yacc, const float* __restrict__ z,
    const float* __restrict__ lng, const float* __restrict__ lnb,
    const float* __restrict__ opw, float* __restrict__ out) {
  __shared__ float ytile[64 * 193];   // 49.4 KB
  __shared__ float Wl[96 * DI];       // 73.7 KB
  const int pt = blockIdx.x, b = blockIdx.y;
  const int t = threadIdx.x;
  // stage out_proj_w: 96*192 = 18432 floats = 4608 float4
  {
    const float4* wsrc = reinterpret_cast<const float4*>(opw);
    float4* wdst = reinterpret_cast<float4*>(Wl);
#pragma unroll
    for (int r = 0; r < 18; ++r) wdst[r * 256 + t] = wsrc[r * 256 + t];
  }
  {
    const int c = t & 63, q4 = t >> 6;
    for (int dd = 0; dd < 48; ++dd) {
      int d = dd * 4 + q4;
      ytile[c * 193 + d] = yacc[((size_t)(b * DI + d)) * LL + pt * 64 + c];
    }
  }
  __syncthreads();
  {
    const int p = t >> 2, qq = t & 3;
    float s = 0.f, s2 = 0.f;
    for (int j = 0; j < 48; ++j) {
      float v = ytile[p * 193 + qq * 48 + j];
      s += v; s2 += v * v;
    }
    s += __shfl_xor(s, 1, 64);  s += __shfl_xor(s, 2, 64);
    s2 += __shfl_xor(s2, 1, 64); s2 += __shfl_xor(s2, 2, 64);
    const float mu = s * (1.f / 192.f);
    const float var = s2 * (1.f / 192.f) - mu * mu;
    const float rstd = rsqrtf(var + 1e-5f);
    const size_t prow = ((size_t)b * LL + pt * 64 + p) * DI;
    for (int j = 0; j < 48; ++j) {
      int d = qq * 48 + j;
      float v = (ytile[p * 193 + d] - mu) * rstd * lng[d] + lnb[d];
      float zv = z[prow + d];
      v *= siluf(zv);
      ytile[p * 193 + d] = v;
    }
  }
  __syncthreads();
  float acc[24];
#pragma unroll
  for (int j = 0; j < 24; ++j) acc[j] = 0.f;
  const int p2 = t & 63, gq = t >> 6;
  for (int dq = 0; dq < 48; ++dq) {
    float xv[4];
#pragma unroll
    for (int e = 0; e < 4; ++e) xv[e] = ytile[p2 * 193 + dq * 4 + e];
#pragma unroll
    for (int j = 0; j < 24; ++j) {
      const float4 wv = *reinterpret_cast<const float4*>(&Wl[(gq * 24 + j) * DI + dq * 4]);
      acc[j] += wv.x * xv[0] + wv.y * xv[1] + wv.z * xv[2] + wv.w * xv[3];
    }
  }
  __syncthreads();
  float* l2 = ytile;  // reuse as [64][97]
#pragma unroll
  for (int j = 0; j < 24; ++j) l2[p2 * 97 + gq * 24 + j] = acc[j];
  __syncthreads();
  for (int rr = 0; rr < 24; ++rr) {
    int idx = rr * 256 + t;
    int pp = idx / 96, cc = idx - pp * 96;
    out[((size_t)b * LL + pt * 64 + pp) * 96 + cc] = l2[pp * 97 + cc];
  }
}

// ---------------------------------------------------------------------------
extern "C" void kernel_launch(void* const* d_in, const int* in_sizes, int n_in,
                              void* d_out, int out_size, void* d_ws, size_t ws_size,
                              hipStream_t stream) {
  const float* x          = (const float*)d_in[0];
  const float* in_proj_w  = (const float*)d_in[1];
  const float* conv_w     = (const float*)d_in[2];
  const float* conv_b     = (const float*)d_in[3];
  const float* x_proj_w   = (const float*)d_in[4];
  const float* dt_projs_w = (const float*)d_in[5];
  const float* dt_projs_b = (const float*)d_in[6];
  const float* A_logs     = (const float*)d_in[7];
  const float* Ds         = (const float*)d_in[8];
  const float* ln_g       = (const float*)d_in[9];
  const float* ln_b       = (const float*)d_in[10];
  const float* out_proj_w = (const float*)d_in[11];
  float* out = (float*)d_out;
  float* ws = (float*)d_ws;
  float* xh   = ws;               // 3145728  (B,L,DI)
  float* z    = ws + 3145728;     // 3145728  (B,L,DI)
  float* u0   = ws + 6291456;     // 3145728  (B,DI,H*W)
  float* u1   = ws + 9437184;     // 3145728  (B,DI,W*H)
  float* dts  = ws + 12582912;    // 393216   (B,K,6,L) scan-transposed
  float* Bsv  = ws + 12976128;    // 1048576  (B,K,16,L)
  float* Csv  = ws + 14024704;    // 1048576
  float* hbuf = ws + 15073280;    // 3145728  (B,K,DI,64,16)
  float* sumd = ws + 18219008;    // 196608   (B,K,DI,64)
  float* yacc = ws + 18415616;    // 3145728  (B,DI,L)

  k_inproj<<<dim3(256, 6), dim3(256), 0, stream>>>(x, in_proj_w, xh, z);
  k_conv<<<dim3(64, 4), dim3(192), 0, stream>>>(xh, conv_w, conv_b, u0);
  k_transpose<<<dim3(768), dim3(256), 0, stream>>>(u0, u1);
  k_xdbl<<<dim3(64, 4, 4), dim3(256), 0, stream>>>(u0, u1, x_proj_w, dts, Bsv, Csv);
  k_scan1<<<dim3(48, 4, 4), dim3(256), 0, stream>>>(u0, u1, dts, Bsv,
      dt_projs_w, dt_projs_b, A_logs, hbuf, sumd);
  k_scan2<<<dim3(192), dim3(256), 0, stream>>>(A_logs, sumd, hbuf);
  k_scan3<0, false><<<dim3(48, 4), dim3(256), 0, stream>>>(u0, u1, dts, Bsv, Csv,
      dt_projs_w, dt_projs_b, A_logs, hbuf, Ds, yacc);
  k_scan3<1, true><<<dim3(48, 4), dim3(256), 0, stream>>>(u0, u1, dts, Bsv, Csv,
      dt_projs_w, dt_projs_b, A_logs, hbuf, Ds, yacc);
  k_scan3<2, true><<<dim3(48, 4), dim3(256), 0, stream>>>(u0, u1, dts, Bsv, Csv,
      dt_projs_w, dt_projs_b, A_logs, hbuf, Ds, yacc);
  k_scan3<3, true><<<dim3(48, 4), dim3(256), 0, stream>>>(u0, u1, dts, Bsv, Csv,
      dt_projs_w, dt_projs_b, A_logs, hbuf, Ds, yacc);
  k_lnout<<<dim3(64, 4), dim3(256), 0, stream>>>(yacc, z, ln_g, ln_b, out_proj_w, out);
}